// Round 12
// baseline (6137.107 us; speedup 1.0000x reference)
//
#include <hip/hip_runtime.h>

typedef float v2f __attribute__((ext_vector_type(2)));

constexpr int T  = 1024;
constexpr int B  = 32;
constexpr int I_ = 64;
constexpr int H  = 1024;
constexpr int OF = 64;
constexpr int OC = 8;
constexpr int NGR = 8;    // groups (4 batches each)
constexpr int NMEM = 32;  // member WGs per group (32 rows each)
constexpr long long OUT1_OFF = (long long)T * B * OF;
constexpr long long OUT2_OFF = (long long)T * B * (OF + OC);
constexpr int RING_U64 = 2 * NGR * 4 * 1024;   // [slot][g][batch][row] = 512 KB

// Agent-scope relaxed ops: global_{load,store} sc0 sc1 — bypass L1/L2,
// coherent at L3, fence-free. Proven (R2/R6/R8/R10/R11). sc0-only polling
// livelocks (R4/R5/R7) — never used.
__device__ __forceinline__ void st_agent_u64(unsigned long long* p,
                                             unsigned long long v) {
  __hip_atomic_store(p, v, __ATOMIC_RELAXED, __HIP_MEMORY_SCOPE_AGENT);
}
__device__ __forceinline__ unsigned long long
ld_agent_u64(const unsigned long long* p) {
  return __hip_atomic_load(p, __ATOMIC_RELAXED, __HIP_MEMORY_SCOPE_AGENT);
}

// ---------------------------------------------------------------------------
// Recurrence: 256 persistent WGs x 1024 threads (1/CU, 16 waves).
// Group g = bid&7 owns batches [4g, 4g+4); member m = bid>>3 owns rows
// [m*32, +32). Thread (r=tid>>5, s=tid&31): row j=m*32+r, k-slice
// {q*64+2s, q*64+2s+1} -> 17 float2 weights (q=16 maps exactly to i2h).
//
// 4-PHASE ROTATION, uniform 2-phase store->check slack:
//   phase y of step t: [issue restage loads for batch p=(y+2)&3, data from
//   step tp=(y<2 ? t-1 : t), slot tp&1, tag tp+1]  ->  compute batch y from
//   lds[y] (r_{t-1}, x_t), producers (s==0) store tagged packets (slot t&1,
//   tag t+1) + plain rate_all  ->  tag-check the early loads (2 compute
//   phases + 2 barriers of slack; spin-reload on stale)  ->  commit r_tp and
//   x_{tp+1} into lds[p]  ->  __syncthreads.
// lds[p] is written only at phase (p+2)&3 and read only at phase p — no
// same-phase read/write overlap; per-phase barrier separates them.
// Lap-safety (2-slot, == tag check): a producer overwrites (slot,batch) at
// step t+2 only after passing checks that require every member's step-t+1
// stores, which program-order-follow that member's consumption of the slot
// at step t => an expected tag can never be skipped. Ring zeroed per call.
// ---------------------------------------------------------------------------
__global__ __launch_bounds__(1024, 1) void rnn_recur(
    const float* __restrict__ input_sig, const float* __restrict__ rate0,
    const float* __restrict__ i2h_w, const float* __restrict__ i2h_b,
    const float* __restrict__ h2h_w, const float* __restrict__ h2h_b,
    float* __restrict__ rate_all, unsigned long long* __restrict__ ring)
{
  const int tid = threadIdx.x;
  const int bid = blockIdx.x;
  const int g   = bid & (NGR - 1);
  const int m   = bid >> 3;
  const int r   = tid >> 5;
  const int s   = tid & 31;
  const int j   = m * 32 + r;
  const int bG  = g * 4;

  __shared__ float lds[4][1088];   // [batch][k]; k>=1024 is x_t

  // ---- register-stationary weights: 17 float2 = 34 fp32/thread
  v2f w2[17];
#pragma unroll
  for (int q = 0; q < 17; ++q) {
    const int k = q * 64 + 2 * s;
    w2[q] = (q < 16) ? *(const v2f*)(h2h_w + (long long)j * H + k)
                     : *(const v2f*)(i2h_w + (long long)j * I_ + (k - H));
  }
  const float bsum = h2h_b[j] + i2h_b[j];

  // ---- init: r_{-1} = rate0, x_0 for all 4 batches (plain cached loads)
#pragma unroll
  for (int y = 0; y < 4; ++y) {
    lds[y][tid] = rate0[(long long)(bG + y) * H + tid];
  }
  if (tid < 256) {
    const int y = tid >> 6, xi = tid & 63;
    lds[y][1024 + xi] = input_sig[(long long)(bG + y) * I_ + xi];
  }
  __syncthreads();

  unsigned long long* ringBase = ring;

  for (int t = 0; t < T; ++t) {
#pragma unroll
    for (int y = 0; y < 4; ++y) {
      // ---- early-issue restage loads: batch p's r_{tp} + x_{tp+1}
      const int p  = (y + 2) & 3;
      const int tp = (y < 2) ? t - 1 : t;
      const bool doR = (tp >= 0) && (tp <= T - 2);
      unsigned long long pkt = 0;
      float4 xv;
      const bool xs = (tid < 16);
      const unsigned long long* ap =
          ringBase + ((((long long)(tp & 1) * NGR + g) * 4 + p) << 10) + tid;
      if (doR) {
        pkt = ld_agent_u64(ap);
        if (xs) {
          xv = *(const float4*)(input_sig +
              ((long long)(tp + 1) * B + bG + p) * I_ + tid * 4);
        }
      }

      // ---- compute batch y: r_t = 0.9 r_{t-1} + 0.1 tanh(W.[r;x] + b)
      v2f acc2 = {0.f, 0.f};
#pragma unroll
      for (int q = 0; q < 17; ++q) {
        const v2f rv = *(const v2f*)&lds[y][q * 64 + 2 * s];
        acc2 = __builtin_elementwise_fma(w2[q], rv, acc2);
      }
      float acc = acc2.x + acc2.y;
      acc += __shfl_xor(acc, 16, 64);
      acc += __shfl_xor(acc, 8, 64);
      acc += __shfl_xor(acc, 4, 64);
      acc += __shfl_xor(acc, 2, 64);
      acc += __shfl_xor(acc, 1, 64);
      if (s == 0) {
        const float pre  = acc + bsum;
        const float rold = lds[y][j];
        const float rnew = 0.9f * rold + 0.1f * tanhf(pre);
        const unsigned long long out =
            ((unsigned long long)(unsigned)(t + 1) << 32) |
            (unsigned long long)__float_as_uint(rnew);
        st_agent_u64(ringBase +
            ((((long long)(t & 1) * NGR + g) * 4 + y) << 10) + j, out);
        rate_all[((long long)t * B + bG + y) * H + j] = rnew;  // plain cached
      }

      // ---- tag-check (loads had ~2 compute phases of slack) + commit
      if (doR) {
        const unsigned tag = (unsigned)(tp + 1);
        while ((unsigned)(pkt >> 32) != tag) pkt = ld_agent_u64(ap);
        lds[p][tid] = __uint_as_float((unsigned)pkt);
        if (xs) *(float4*)&lds[p][1024 + tid * 4] = xv;
      }
      __syncthreads();
    }
  }
}

// ---------------------------------------------------------------------------
// Readout: C[32768,72] = rate_all[32768,1024] x [h2o_w;h2o_ctx_w]^T + bias
// ---------------------------------------------------------------------------
__global__ __launch_bounds__(256) void rnn_readout(
    const float* __restrict__ rate_all,
    const float* __restrict__ h2o_w, const float* __restrict__ h2o_b,
    const float* __restrict__ h2o_ctx_w, const float* __restrict__ h2o_ctx_b,
    float* __restrict__ out0, float* __restrict__ out1)
{
  constexpr int RB = 128;
  constexpr int HC = 128;
  constexpr int SR = HC + 1;
  __shared__ float rl[RB * SR];
  __shared__ float wl[72 * SR];

  const int tid = threadIdx.x;
  const long long row0 = (long long)blockIdx.x * RB;
  const int rb = tid & 31, og = tid >> 5;

  float acc[4][9];
#pragma unroll
  for (int c = 0; c < 4; ++c)
#pragma unroll
    for (int i = 0; i < 9; ++i) acc[c][i] = 0.f;

  for (int hc = 0; hc < H / HC; ++hc) {
#pragma unroll
    for (int i = 0; i < 16; ++i) {
      const int q = i * 256 + tid;
      const int row = q >> 5, hq = q & 31;
      float4 v = *(const float4*)(rate_all + (row0 + row) * H + hc * HC + hq * 4);
      float* d = &rl[row * SR + hq * 4];
      d[0] = v.x; d[1] = v.y; d[2] = v.z; d[3] = v.w;
    }
#pragma unroll
    for (int i = 0; i < 9; ++i) {
      const int q = i * 256 + tid;
      const int o = q >> 5, hq = q & 31;
      const float* src = (o < OF) ? (h2o_w + (long long)o * H)
                                  : (h2o_ctx_w + (long long)(o - OF) * H);
      float4 v = *(const float4*)(src + hc * HC + hq * 4);
      float* d = &wl[o * SR + hq * 4];
      d[0] = v.x; d[1] = v.y; d[2] = v.z; d[3] = v.w;
    }
    __syncthreads();

#pragma unroll 4
    for (int h = 0; h < HC; ++h) {
      const float r0 = rl[(rb)      * SR + h];
      const float r1 = rl[(rb + 32) * SR + h];
      const float r2 = rl[(rb + 64) * SR + h];
      const float r3 = rl[(rb + 96) * SR + h];
#pragma unroll
      for (int i = 0; i < 9; ++i) {
        const float wv = wl[(og * 9 + i) * SR + h];
        acc[0][i] = fmaf(r0, wv, acc[0][i]);
        acc[1][i] = fmaf(r1, wv, acc[1][i]);
        acc[2][i] = fmaf(r2, wv, acc[2][i]);
        acc[3][i] = fmaf(r3, wv, acc[3][i]);
      }
    }
    __syncthreads();
  }

#pragma unroll
  for (int c = 0; c < 4; ++c) {
    const long long row = row0 + rb + 32 * c;
#pragma unroll
    for (int i = 0; i < 9; ++i) {
      const int o = og * 9 + i;
      if (o < OF) out0[row * OF + o] = acc[c][i] + h2o_b[o];
      else        out1[row * OC + (o - OF)] = acc[c][i] + h2o_ctx_b[o - OF];
    }
  }
}

extern "C" void kernel_launch(void* const* d_in, const int* in_sizes, int n_in,
                              void* d_out, int out_size, void* d_ws, size_t ws_size,
                              hipStream_t stream) {
  (void)in_sizes; (void)n_in; (void)d_ws; (void)ws_size; (void)out_size;
  const float* input_sig = (const float*)d_in[0];
  const float* rate0     = (const float*)d_in[1];
  const float* i2h_w     = (const float*)d_in[2];
  const float* i2h_b     = (const float*)d_in[3];
  const float* h2h_w     = (const float*)d_in[4];
  const float* h2h_b     = (const float*)d_in[5];
  const float* h2o_w     = (const float*)d_in[6];
  const float* h2o_b     = (const float*)d_in[7];
  const float* h2o_ctx_w = (const float*)d_in[8];
  const float* h2o_ctx_b = (const float*)d_in[9];

  float* out      = (float*)d_out;
  float* out0     = out;
  float* out1     = out + OUT1_OFF;
  float* rate_all = out + OUT2_OFF;
  // Tagged 2-slot ring in the first 512 KB of out0 (overwritten by readout).
  unsigned long long* ring = (unsigned long long*)d_out;

  // Zero the ring EVERY call: expected tags are >=1, so zero never matches;
  // stale tags from a previous call/graph-replay would otherwise alias.
  hipMemsetAsync(ring, 0, (size_t)RING_U64 * 8, stream);
  hipLaunchKernelGGL(rnn_recur, dim3(NGR * NMEM), dim3(1024), 0, stream,
                     input_sig, rate0, i2h_w, i2h_b, h2h_w, h2h_b,
                     rate_all, ring);
  hipLaunchKernelGGL(rnn_readout, dim3(256), dim3(256), 0, stream,
                     rate_all, h2o_w, h2o_b, h2o_ctx_w, h2o_ctx_b, out0, out1);
}

// Round 13
// 3815.266 us; speedup vs baseline: 1.6086x; 1.6086x over previous
//
#include <hip/hip_runtime.h>

typedef float v2f __attribute__((ext_vector_type(2)));
typedef float v4f __attribute__((ext_vector_type(4)));

constexpr int T  = 1024;
constexpr int B  = 32;
constexpr int I_ = 64;
constexpr int H  = 1024;
constexpr int OF = 64;
constexpr int OC = 8;
constexpr int NG = 16;    // groups (2 batches each)
constexpr int NM = 16;    // member WGs per group (64 rows each)
constexpr int CHK = 128;  // per-lane k-chunk (1024/8, h2h only — i2h precomputed)
constexpr int CHP = 132;  // padded chunk stride: 4*l8 mod 32 spans all bank quads
constexpr int BSTR = 8 * CHP;
constexpr long long OUT1_OFF = (long long)T * B * OF;
constexpr long long OUT2_OFF = (long long)T * B * (OF + OC);
constexpr int RING_U64 = NG * 2 * 2 * 1024;  // [g][slot][b][row] = 512 KB

// Agent-scope relaxed ops: global_{load,store} sc0 sc1 — bypass L1/L2,
// coherent at L3, fence-free. Proven (R2/R6/R10/R11). sc0-only polling
// livelocks (R4/R5/R7) — never used.
__device__ __forceinline__ void st_agent_u64(unsigned long long* p,
                                             unsigned long long v) {
  __hip_atomic_store(p, v, __ATOMIC_RELAXED, __HIP_MEMORY_SCOPE_AGENT);
}
__device__ __forceinline__ unsigned long long
ld_agent_u64(const unsigned long long* p) {
  return __hip_atomic_load(p, __ATOMIC_RELAXED, __HIP_MEMORY_SCOPE_AGENT);
}

// ---------------------------------------------------------------------------
// x_proj precompute: xp[t,b,h] = dot(input_sig[t,b,:], i2h_w[h,:]) written
// INTO the rate_all region — each element is read exactly once (by its owner
// thread at step t) and then overwritten by r_new at the same address in the
// same thread (read-before-write in program order => race-free).
// 4096 blocks x 256 thr; block = 8 (t,b)-rows; thread = 4 h columns.
// ---------------------------------------------------------------------------
__global__ __launch_bounds__(256) void xproj_kern(
    const float* __restrict__ input_sig, const float* __restrict__ i2h_w,
    float* __restrict__ xp)
{
  __shared__ float X[8][64];
  const int tid = threadIdx.x;
  const long long row0 = (long long)blockIdx.x * 8;
  if (tid < 128) {
    const int r = tid >> 4, e = tid & 15;
    *(float4*)&X[r][e * 4] = *(const float4*)(input_sig + (row0 + r) * I_ + e * 4);
  }
  __syncthreads();
#pragma unroll
  for (int hh = 0; hh < 4; ++hh) {
    const int h = hh * 256 + tid;
    const float4* wp = (const float4*)(i2h_w + (long long)h * I_);
    float acc[8] = {0.f, 0.f, 0.f, 0.f, 0.f, 0.f, 0.f, 0.f};
#pragma unroll
    for (int kq = 0; kq < 16; ++kq) {
      const float4 wv = wp[kq];
#pragma unroll
      for (int r = 0; r < 8; ++r) {
        acc[r] = fmaf(wv.x, X[r][kq * 4 + 0],
                 fmaf(wv.y, X[r][kq * 4 + 1],
                 fmaf(wv.z, X[r][kq * 4 + 2],
                 fmaf(wv.w, X[r][kq * 4 + 3], acc[r]))));
      }
    }
#pragma unroll
    for (int r = 0; r < 8; ++r) xp[(row0 + r) * H + h] = acc[r];
  }
}

// ---------------------------------------------------------------------------
// Recurrence: 256 persistent WGs x 512 threads (1/CU, 8 waves,
// launch_bounds(512,1) -> 256-VGPR budget so the 128 weight floats live in
// ArchVGPRs — no AGPR shuffling (R8/R11 lesson; VGPR_Count is the check).
// Group g = bid&15 owns batches {2g,2g+1}; member m = bid>>4 owns rows
// [m*64,+64). Thread (jrel=tid>>3, l8=tid&7): row j, k-chunk [l8*128,+128),
// 64 float2 weights. x_proj preloaded from rate_all (see xproj_kern).
//
// Exchange: tagged u64 packets {u32 tag=t+1 | f32 val}, 2-slot ring; data
// load IS the sync (R10/R11-proven). Ping-pong + early issue:
//   [issue L1: b1 r_t (stored a FULL step ago) ; prefetch xp0,xp1]
//   C0(t) -> packets ; [issue L0: b0 r_t packets, max flight time]
//   check L1 -> commit lds[1] ; barrier
//   C1(t) -> packets ; check L0 -> commit lds[0] ; barrier
// Check positions = R10/R11 => same liveness/lap-safety induction. Stale
// early reads just re-poll. Ring zeroed per call (tags >= 1).
// ---------------------------------------------------------------------------
__global__ __launch_bounds__(512, 1) void rnn_recur(
    const float* __restrict__ rate0, const float* __restrict__ h2h_w,
    const float* __restrict__ i2h_b, const float* __restrict__ h2h_b,
    float* __restrict__ rate_all, unsigned long long* __restrict__ ring)
{
  const int tid = threadIdx.x;
  const int bid = blockIdx.x;
  const int g   = bid & (NG - 1);
  const int m   = bid >> 4;
  const int l8  = tid & 7;
  const int jrel = tid >> 3;
  const int j   = m * 64 + jrel;
  const int bG  = g * 2;

  __shared__ float lds[2][BSTR];   // [batch][padded 8x132 chunks]

  // ---- register-stationary weights: 64 float2 = 128 fp32/thread (h2h only)
  v2f w2[64];
#pragma unroll
  for (int q = 0; q < 64; ++q) {
    w2[q] = *(const v2f*)(h2h_w + (long long)j * H + l8 * CHK + q * 2);
  }
  const float bsum = h2h_b[j] + i2h_b[j];
  const int posj = (j >> 7) * CHP + (j & 127);

  // ---- init: r_{-1} = rate0 for both batches (plain cached loads)
  {
    const int b = tid >> 8, u = tid & 255;
    const int k0 = u * 4, c = k0 >> 7, off = k0 & 127;
    *(float4*)&lds[b][c * CHP + off] =
        *(const float4*)(rate0 + (long long)(bG + b) * H + k0);
  }
  __syncthreads();

  unsigned long long* ringG = ring + (long long)g * (2 * 2 * 1024);
  const int c_  = tid >> 6;
  const int off_ = 2 * tid - c_ * CHK;

  // matvec over lds[b] (+xp scalar), publish tagged packets + rate_all
  auto phase = [&](int b, int t, float xp) {
    const float* Rb = &lds[b][0];
    v2f acc2 = {0.f, 0.f};
#pragma unroll
    for (int q = 0; q < 32; ++q) {
      const v4f rv = *(const v4f*)&Rb[l8 * CHP + q * 4];
      const v2f rlo = __builtin_shufflevector(rv, rv, 0, 1);
      const v2f rhi = __builtin_shufflevector(rv, rv, 2, 3);
      acc2 = __builtin_elementwise_fma(w2[2 * q],     rlo, acc2);
      acc2 = __builtin_elementwise_fma(w2[2 * q + 1], rhi, acc2);
    }
    float acc = acc2.x + acc2.y;
    acc += __shfl_xor(acc, 4, 64);
    acc += __shfl_xor(acc, 2, 64);
    acc += __shfl_xor(acc, 1, 64);
    if (l8 == 0) {
      const float pre  = acc + xp + bsum;
      const float rold = Rb[posj];
      const float rnew = 0.9f * rold + 0.1f * tanhf(pre);
      const unsigned long long pkt =
          ((unsigned long long)(unsigned)(t + 1) << 32) |
          (unsigned long long)__float_as_uint(rnew);
      st_agent_u64(&ringG[((long long)((t & 1) * 2 + b) << 10) + j], pkt);
      rate_all[((long long)t * B + bG + b) * H + j] = rnew;  // overwrites xp
    }
  };

  for (int t = 0; t < T; ++t) {
    // ---- prefetch xp scalars (owner-consumed; same addr across the 8 lanes)
    const float xp0 = rate_all[((long long)t * B + bG) * H + j];
    const float xp1 = rate_all[((long long)t * B + bG + 1) * H + j];

    // ---- early-issue L1: b1's r_t (slot (t-1)&1, tag t — a full step old)
    unsigned long long v10 = 0, v11 = 0;
    const bool have1 = (t > 0);
    const unsigned long long* p1 =
        &ringG[((long long)((((t - 1) & 1) * 2) + 1) << 10) + 2 * tid];
    if (have1) { v10 = ld_agent_u64(p1); v11 = ld_agent_u64(p1 + 1); }

    phase(0, t, xp0);   // C0(t)

    // ---- early-issue L0 right after C0's stores: maximal flight time
    unsigned long long v00 = 0, v01 = 0;
    const bool have0 = (t + 1 < T);
    const unsigned long long* p0 =
        &ringG[((long long)((t & 1) * 2) << 10) + 2 * tid];
    if (have0) { v00 = ld_agent_u64(p0); v01 = ld_agent_u64(p0 + 1); }

    if (have1) {
      const unsigned tag = (unsigned)t;
      while ((unsigned)(v10 >> 32) != tag || (unsigned)(v11 >> 32) != tag) {
        v10 = ld_agent_u64(p1);
        v11 = ld_agent_u64(p1 + 1);
      }
      *(float2*)&lds[1][c_ * CHP + off_] = make_float2(
          __uint_as_float((unsigned)v10), __uint_as_float((unsigned)v11));
    }
    __syncthreads();

    phase(1, t, xp1);   // C1(t)

    if (have0) {
      const unsigned tag = (unsigned)(t + 1);
      while ((unsigned)(v00 >> 32) != tag || (unsigned)(v01 >> 32) != tag) {
        v00 = ld_agent_u64(p0);
        v01 = ld_agent_u64(p0 + 1);
      }
      *(float2*)&lds[0][c_ * CHP + off_] = make_float2(
          __uint_as_float((unsigned)v00), __uint_as_float((unsigned)v01));
    }
    __syncthreads();
  }
}

// ---------------------------------------------------------------------------
// Readout: C[32768,72] = rate_all[32768,1024] x [h2o_w;h2o_ctx_w]^T + bias
// ---------------------------------------------------------------------------
__global__ __launch_bounds__(256) void rnn_readout(
    const float* __restrict__ rate_all,
    const float* __restrict__ h2o_w, const float* __restrict__ h2o_b,
    const float* __restrict__ h2o_ctx_w, const float* __restrict__ h2o_ctx_b,
    float* __restrict__ out0, float* __restrict__ out1)
{
  constexpr int RB = 128;
  constexpr int HC = 128;
  constexpr int SR = HC + 1;
  __shared__ float rl[RB * SR];
  __shared__ float wl[72 * SR];

  const int tid = threadIdx.x;
  const long long row0 = (long long)blockIdx.x * RB;
  const int rb = tid & 31, og = tid >> 5;

  float acc[4][9];
#pragma unroll
  for (int c = 0; c < 4; ++c)
#pragma unroll
    for (int i = 0; i < 9; ++i) acc[c][i] = 0.f;

  for (int hc = 0; hc < H / HC; ++hc) {
#pragma unroll
    for (int i = 0; i < 16; ++i) {
      const int q = i * 256 + tid;
      const int row = q >> 5, hq = q & 31;
      float4 v = *(const float4*)(rate_all + (row0 + row) * H + hc * HC + hq * 4);
      float* d = &rl[row * SR + hq * 4];
      d[0] = v.x; d[1] = v.y; d[2] = v.z; d[3] = v.w;
    }
#pragma unroll
    for (int i = 0; i < 9; ++i) {
      const int q = i * 256 + tid;
      const int o = q >> 5, hq = q & 31;
      const float* src = (o < OF) ? (h2o_w + (long long)o * H)
                                  : (h2o_ctx_w + (long long)(o - OF) * H);
      float4 v = *(const float4*)(src + hc * HC + hq * 4);
      float* d = &wl[o * SR + hq * 4];
      d[0] = v.x; d[1] = v.y; d[2] = v.z; d[3] = v.w;
    }
    __syncthreads();

#pragma unroll 4
    for (int h = 0; h < HC; ++h) {
      const float r0 = rl[(rb)      * SR + h];
      const float r1 = rl[(rb + 32) * SR + h];
      const float r2 = rl[(rb + 64) * SR + h];
      const float r3 = rl[(rb + 96) * SR + h];
#pragma unroll
      for (int i = 0; i < 9; ++i) {
        const float wv = wl[(og * 9 + i) * SR + h];
        acc[0][i] = fmaf(r0, wv, acc[0][i]);
        acc[1][i] = fmaf(r1, wv, acc[1][i]);
        acc[2][i] = fmaf(r2, wv, acc[2][i]);
        acc[3][i] = fmaf(r3, wv, acc[3][i]);
      }
    }
    __syncthreads();
  }

#pragma unroll
  for (int c = 0; c < 4; ++c) {
    const long long row = row0 + rb + 32 * c;
#pragma unroll
    for (int i = 0; i < 9; ++i) {
      const int o = og * 9 + i;
      if (o < OF) out0[row * OF + o] = acc[c][i] + h2o_b[o];
      else        out1[row * OC + (o - OF)] = acc[c][i] + h2o_ctx_b[o - OF];
    }
  }
}

extern "C" void kernel_launch(void* const* d_in, const int* in_sizes, int n_in,
                              void* d_out, int out_size, void* d_ws, size_t ws_size,
                              hipStream_t stream) {
  (void)in_sizes; (void)n_in; (void)d_ws; (void)ws_size; (void)out_size;
  const float* input_sig = (const float*)d_in[0];
  const float* rate0     = (const float*)d_in[1];
  const float* i2h_w     = (const float*)d_in[2];
  const float* i2h_b     = (const float*)d_in[3];
  const float* h2h_w     = (const float*)d_in[4];
  const float* h2h_b     = (const float*)d_in[5];
  const float* h2o_w     = (const float*)d_in[6];
  const float* h2o_b     = (const float*)d_in[7];
  const float* h2o_ctx_w = (const float*)d_in[8];
  const float* h2o_ctx_b = (const float*)d_in[9];

  float* out      = (float*)d_out;
  float* out0     = out;
  float* out1     = out + OUT1_OFF;
  float* rate_all = out + OUT2_OFF;
  // Tagged 2-slot ring in the first 512 KB of out0 (overwritten by readout).
  unsigned long long* ring = (unsigned long long*)d_out;

  // Zero the ring EVERY call: expected tags are >=1, so zero never matches.
  hipMemsetAsync(ring, 0, (size_t)RING_U64 * 8, stream);
  // x_proj -> rate_all region (each value read once, then overwritten by rnew)
  hipLaunchKernelGGL(xproj_kern, dim3(T * B / 8), dim3(256), 0, stream,
                     input_sig, i2h_w, rate_all);
  hipLaunchKernelGGL(rnn_recur, dim3(NG * NM), dim3(512), 0, stream,
                     rate0, h2h_w, i2h_b, h2h_b, rate_all, ring);
  hipLaunchKernelGGL(rnn_readout, dim3(256), dim3(256), 0, stream,
                     rate_all, h2o_w, h2o_b, h2o_ctx_w, h2o_ctx_b, out0, out1);
}

// Round 14
// 2408.114 us; speedup vs baseline: 2.5485x; 1.5843x over previous
//
#include <hip/hip_runtime.h>

typedef float v2f __attribute__((ext_vector_type(2)));
typedef float v4f __attribute__((ext_vector_type(4)));

constexpr int T  = 1024;
constexpr int B  = 32;
constexpr int I_ = 64;
constexpr int H  = 1024;
constexpr int OF = 64;
constexpr int OC = 8;
constexpr int NG = 16;   // groups (2 batches each)
constexpr int NM = 16;   // member WGs per group (64 rows each)
constexpr int CH  = 136; // per-lane contiguous k-chunk (1088/8)
constexpr int CHP = 140; // padded chunk stride (12*l8 mod 32 -> all banks)
constexpr int BSTR = 8 * CHP;
constexpr long long OUT1_OFF = (long long)T * B * OF;
constexpr long long OUT2_OFF = (long long)T * B * (OF + OC);
constexpr int RING_U64 = NG * 2 * 2 * 1024;  // [g][slot][b][elem] = 512 KB

// Agent-scope relaxed ops: global_{load,store} sc0 sc1 — bypass L1/L2,
// coherent at L3, fence-free. Proven (R2/R6/R10/R11). sc0-only polling
// livelocks (R4/R5/R7) — never used.
__device__ __forceinline__ void st_agent_u64(unsigned long long* p,
                                             unsigned long long v) {
  __hip_atomic_store(p, v, __ATOMIC_RELAXED, __HIP_MEMORY_SCOPE_AGENT);
}
__device__ __forceinline__ unsigned long long
ld_agent_u64(const unsigned long long* p) {
  return __hip_atomic_load(p, __ATOMIC_RELAXED, __HIP_MEMORY_SCOPE_AGENT);
}

// ---------------------------------------------------------------------------
// Recurrence: 256 persistent WGs x 512 threads (1/CU).
// Group g = bid&15 owns batches {2g, 2g+1}; member m = bid>>4 owns rows
// [m*64, m*64+64). Thread (jrel=tid>>3, l8=tid&7): row j=m*64+jrel, k-chunk
// [l8*136, +136). Weights register/AGPR-stationary as 68 float2 (pk-FMA; on
// CDNA4 VALU sources AGPRs directly, so AGPR residency is free).
//
// Exchange: tagged u64 packets {u32 tag=t+1 | f32 val}, 2-slot ring
// (slot=t&1); the data load IS the sync. PING-PONG + TIMED PROBES:
//   issue L1 loads (b1 r_t, stored a FULL STEP ago) + x_t(b1)
//   C0(t): pk-FMA matvec b0, store packets (tag t+1, slot t&1)
//   check L1 (flew under C0) -> commit lds[1]; barrier
//   C1(t) FIRST HALF (17 q-steps)
//   issue L0 loads MID-PHASE (samples the L3 line ~0.4us after C0's stores,
//     past the ~0.3us visibility horizon -> first-try tag hit; R11 issued at
//     +0 and always sampled stale, paying a ~0.4us re-poll every step)
//   C1(t) SECOND HALF + reduce + store packets
//   check L0 -> commit lds[0]; barrier
// Check positions identical to R10/R11 => same liveness/lap-safety induction
// (slot overwrite at tag+2 is gated through every member's completed check of
// the old tag). Stale probes just fall into the proven re-poll loop. Ring
// zeroed every call (tags >= 1 never match zero).
// ---------------------------------------------------------------------------
__global__ __launch_bounds__(512, 2) void rnn_recur(
    const float* __restrict__ input_sig, const float* __restrict__ rate0,
    const float* __restrict__ i2h_w, const float* __restrict__ i2h_b,
    const float* __restrict__ h2h_w, const float* __restrict__ h2h_b,
    float* __restrict__ rate_all, unsigned long long* __restrict__ ring)
{
  const int tid = threadIdx.x;
  const int bid = blockIdx.x;
  const int g   = bid & (NG - 1);
  const int m   = bid >> 4;
  const int l8  = tid & 7;
  const int jrel = tid >> 3;
  const int j   = m * 64 + jrel;
  const int bG  = g * 2;

  __shared__ float lds[2][BSTR];   // [batch][padded chunks]

  // ---- stationary weights: 68 float2 = 136 fp32/thread
  v2f w2[68];
#pragma unroll
  for (int q = 0; q < 68; ++q) {
    const int k = l8 * CH + q * 2;
    w2[q] = (k < H) ? *(const v2f*)(h2h_w + (long long)j * H + k)
                    : *(const v2f*)(i2h_w + (long long)j * I_ + (k - H));
  }
  const float bsum = h2h_b[j] + i2h_b[j];
  const int posj = (j / CH) * CHP + (j % CH);

  // ---- init: r_{-1} = rate0 and x_0 for both batches (plain cached loads)
  {
    const int b = tid >> 8, u4 = tid & 255;
    const int k0 = u4 * 4, c = k0 / CH, off = k0 - c * CH;
    float4 v = *(const float4*)(rate0 + (long long)(bG + b) * H + k0);
    *(float4*)&lds[b][c * CHP + off] = v;
    if (tid < 32) {
      const int b2 = tid >> 4, iq = tid & 15;
      float4 u = *(const float4*)(input_sig + (long long)(bG + b2) * I_ + iq * 4);
      *(float4*)&lds[b2][7 * CHP + 72 + iq * 4] = u;
    }
  }
  __syncthreads();

  unsigned long long* ringG = ring + (long long)g * (2 * 2 * 1024);
  const int c_  = (2 * tid) / CH;
  const int off_ = 2 * tid - c_ * CH;

  // full compute for batch b at step t (used for phase 0)
  auto phase = [&](int b, int t) {
    const float* Rb = &lds[b][0];
    v2f acc2 = {0.f, 0.f};
#pragma unroll
    for (int q = 0; q < 34; ++q) {
      const v4f rv = *(const v4f*)&Rb[l8 * CHP + q * 4];
      const v2f rlo = __builtin_shufflevector(rv, rv, 0, 1);
      const v2f rhi = __builtin_shufflevector(rv, rv, 2, 3);
      acc2 = __builtin_elementwise_fma(w2[2 * q],     rlo, acc2);
      acc2 = __builtin_elementwise_fma(w2[2 * q + 1], rhi, acc2);
    }
    float acc = acc2.x + acc2.y;
    acc += __shfl_xor(acc, 4, 64);
    acc += __shfl_xor(acc, 2, 64);
    acc += __shfl_xor(acc, 1, 64);
    if (l8 == 0) {
      const float pre  = acc + bsum;
      const float rold = Rb[posj];
      const float rnew = 0.9f * rold + 0.1f * tanhf(pre);
      const unsigned long long pkt =
          ((unsigned long long)(unsigned)(t + 1) << 32) |
          (unsigned long long)__float_as_uint(rnew);
      st_agent_u64(&ringG[((long long)((t & 1) * 2 + b) << 10) + j], pkt);
      rate_all[((long long)t * B + bG + b) * H + j] = rnew;  // plain cached
    }
  };

  for (int t = 0; t < T; ++t) {
    // ---- early-issue L1: b1's r_t (slot (t-1)&1, tag t — a full step old)
    unsigned long long v10 = 0, v11 = 0;
    float4 xv1;
    const bool have1 = (t > 0);
    const unsigned long long* p1 =
        &ringG[((long long)((((t - 1) & 1) * 2) + 1) << 10) + 2 * tid];
    if (have1) {
      v10 = ld_agent_u64(p1);
      v11 = ld_agent_u64(p1 + 1);
      if (tid < 16) {
        xv1 = *(const float4*)(input_sig +
            ((long long)t * B + bG + 1) * I_ + tid * 4);
      }
    }

    phase(0, t);   // C0(t): L1 loads fly under this

    if (have1) {
      const unsigned tag = (unsigned)t;
      while ((unsigned)(v10 >> 32) != tag || (unsigned)(v11 >> 32) != tag) {
        v10 = ld_agent_u64(p1);
        v11 = ld_agent_u64(p1 + 1);
      }
      *(float2*)&lds[1][c_ * CHP + off_] = make_float2(
          __uint_as_float((unsigned)v10), __uint_as_float((unsigned)v11));
      if (tid < 16) *(float4*)&lds[1][7 * CHP + 72 + tid * 4] = xv1;
    }
    __syncthreads();

    // ---- C1(t) inline, with MID-PHASE L0 issue ------------------------
    const float* Rb = &lds[1][0];
    v2f acc2 = {0.f, 0.f};
#pragma unroll
    for (int q = 0; q < 17; ++q) {            // first half
      const v4f rv = *(const v4f*)&Rb[l8 * CHP + q * 4];
      const v2f rlo = __builtin_shufflevector(rv, rv, 0, 1);
      const v2f rhi = __builtin_shufflevector(rv, rv, 2, 3);
      acc2 = __builtin_elementwise_fma(w2[2 * q],     rlo, acc2);
      acc2 = __builtin_elementwise_fma(w2[2 * q + 1], rhi, acc2);
    }
    // mid-phase probe: samples L3 ~0.4us after C0's stores (past visibility)
    unsigned long long v00 = 0, v01 = 0;
    float4 xv0;
    const bool have0 = (t + 1 < T);
    const unsigned long long* p0 =
        &ringG[((long long)((t & 1) * 2) << 10) + 2 * tid];
    if (have0) {
      v00 = ld_agent_u64(p0);
      v01 = ld_agent_u64(p0 + 1);
      if (tid < 16) {
        xv0 = *(const float4*)(input_sig +
            ((long long)(t + 1) * B + bG) * I_ + tid * 4);
      }
    }
    __builtin_amdgcn_sched_barrier(0);        // pin the probe issue point
#pragma unroll
    for (int q = 17; q < 34; ++q) {           // second half
      const v4f rv = *(const v4f*)&Rb[l8 * CHP + q * 4];
      const v2f rlo = __builtin_shufflevector(rv, rv, 0, 1);
      const v2f rhi = __builtin_shufflevector(rv, rv, 2, 3);
      acc2 = __builtin_elementwise_fma(w2[2 * q],     rlo, acc2);
      acc2 = __builtin_elementwise_fma(w2[2 * q + 1], rhi, acc2);
    }
    float acc = acc2.x + acc2.y;
    acc += __shfl_xor(acc, 4, 64);
    acc += __shfl_xor(acc, 2, 64);
    acc += __shfl_xor(acc, 1, 64);
    if (l8 == 0) {
      const float pre  = acc + bsum;
      const float rold = Rb[posj];
      const float rnew = 0.9f * rold + 0.1f * tanhf(pre);
      const unsigned long long pkt =
          ((unsigned long long)(unsigned)(t + 1) << 32) |
          (unsigned long long)__float_as_uint(rnew);
      st_agent_u64(&ringG[((long long)((t & 1) * 2 + 1) << 10) + j], pkt);
      rate_all[((long long)t * B + bG + 1) * H + j] = rnew;  // plain cached
    }

    if (have0) {
      const unsigned tag = (unsigned)(t + 1);
      while ((unsigned)(v00 >> 32) != tag || (unsigned)(v01 >> 32) != tag) {
        v00 = ld_agent_u64(p0);
        v01 = ld_agent_u64(p0 + 1);
      }
      *(float2*)&lds[0][c_ * CHP + off_] = make_float2(
          __uint_as_float((unsigned)v00), __uint_as_float((unsigned)v01));
      if (tid < 16) *(float4*)&lds[0][7 * CHP + 72 + tid * 4] = xv0;
    }
    __syncthreads();
  }
}

// ---------------------------------------------------------------------------
// Readout: C[32768,72] = rate_all[32768,1024] x [h2o_w;h2o_ctx_w]^T + bias
// ---------------------------------------------------------------------------
__global__ __launch_bounds__(256) void rnn_readout(
    const float* __restrict__ rate_all,
    const float* __restrict__ h2o_w, const float* __restrict__ h2o_b,
    const float* __restrict__ h2o_ctx_w, const float* __restrict__ h2o_ctx_b,
    float* __restrict__ out0, float* __restrict__ out1)
{
  constexpr int RB = 128;
  constexpr int HC = 128;
  constexpr int SR = HC + 1;
  __shared__ float rl[RB * SR];
  __shared__ float wl[72 * SR];

  const int tid = threadIdx.x;
  const long long row0 = (long long)blockIdx.x * RB;
  const int rb = tid & 31, og = tid >> 5;

  float acc[4][9];
#pragma unroll
  for (int c = 0; c < 4; ++c)
#pragma unroll
    for (int i = 0; i < 9; ++i) acc[c][i] = 0.f;

  for (int hc = 0; hc < H / HC; ++hc) {
#pragma unroll
    for (int i = 0; i < 16; ++i) {
      const int q = i * 256 + tid;
      const int row = q >> 5, hq = q & 31;
      float4 v = *(const float4*)(rate_all + (row0 + row) * H + hc * HC + hq * 4);
      float* d = &rl[row * SR + hq * 4];
      d[0] = v.x; d[1] = v.y; d[2] = v.z; d[3] = v.w;
    }
#pragma unroll
    for (int i = 0; i < 9; ++i) {
      const int q = i * 256 + tid;
      const int o = q >> 5, hq = q & 31;
      const float* src = (o < OF) ? (h2o_w + (long long)o * H)
                                  : (h2o_ctx_w + (long long)(o - OF) * H);
      float4 v = *(const float4*)(src + hc * HC + hq * 4);
      float* d = &wl[o * SR + hq * 4];
      d[0] = v.x; d[1] = v.y; d[2] = v.z; d[3] = v.w;
    }
    __syncthreads();

#pragma unroll 4
    for (int h = 0; h < HC; ++h) {
      const float r0 = rl[(rb)      * SR + h];
      const float r1 = rl[(rb + 32) * SR + h];
      const float r2 = rl[(rb + 64) * SR + h];
      const float r3 = rl[(rb + 96) * SR + h];
#pragma unroll
      for (int i = 0; i < 9; ++i) {
        const float wv = wl[(og * 9 + i) * SR + h];
        acc[0][i] = fmaf(r0, wv, acc[0][i]);
        acc[1][i] = fmaf(r1, wv, acc[1][i]);
        acc[2][i] = fmaf(r2, wv, acc[2][i]);
        acc[3][i] = fmaf(r3, wv, acc[3][i]);
      }
    }
    __syncthreads();
  }

#pragma unroll
  for (int c = 0; c < 4; ++c) {
    const long long row = row0 + rb + 32 * c;
#pragma unroll
    for (int i = 0; i < 9; ++i) {
      const int o = og * 9 + i;
      if (o < OF) out0[row * OF + o] = acc[c][i] + h2o_b[o];
      else        out1[row * OC + (o - OF)] = acc[c][i] + h2o_ctx_b[o - OF];
    }
  }
}

extern "C" void kernel_launch(void* const* d_in, const int* in_sizes, int n_in,
                              void* d_out, int out_size, void* d_ws, size_t ws_size,
                              hipStream_t stream) {
  (void)in_sizes; (void)n_in; (void)d_ws; (void)ws_size; (void)out_size;
  const float* input_sig = (const float*)d_in[0];
  const float* rate0     = (const float*)d_in[1];
  const float* i2h_w     = (const float*)d_in[2];
  const float* i2h_b     = (const float*)d_in[3];
  const float* h2h_w     = (const float*)d_in[4];
  const float* h2h_b     = (const float*)d_in[5];
  const float* h2o_w     = (const float*)d_in[6];
  const float* h2o_b     = (const float*)d_in[7];
  const float* h2o_ctx_w = (const float*)d_in[8];
  const float* h2o_ctx_b = (const float*)d_in[9];

  float* out      = (float*)d_out;
  float* out0     = out;
  float* out1     = out + OUT1_OFF;
  float* rate_all = out + OUT2_OFF;
  // Tagged 2-slot ring in the first 512 KB of out0 (overwritten by readout).
  unsigned long long* ring = (unsigned long long*)d_out;

  // Zero the ring EVERY call: expected tags are >=1, so zero never matches;
  // stale tags from a previous call/graph-replay would otherwise alias.
  hipMemsetAsync(ring, 0, (size_t)RING_U64 * 8, stream);
  hipLaunchKernelGGL(rnn_recur, dim3(NG * NM), dim3(512), 0, stream,
                     input_sig, rate0, i2h_w, i2h_b, h2h_w, h2h_b,
                     rate_all, ring);
  hipLaunchKernelGGL(rnn_readout, dim3(256), dim3(256), 0, stream,
                     rate_all, h2o_w, h2o_b, h2o_ctx_w, h2o_ctx_b, out0, out1);
}

// Round 15
// 2368.930 us; speedup vs baseline: 2.5907x; 1.0165x over previous
//
#include <hip/hip_runtime.h>

typedef float v2f __attribute__((ext_vector_type(2)));
typedef float v4f __attribute__((ext_vector_type(4)));

constexpr int T  = 1024;
constexpr int B  = 32;
constexpr int I_ = 64;
constexpr int H  = 1024;
constexpr int OF = 64;
constexpr int OC = 8;
constexpr int NG = 16;   // groups (2 batches each)
constexpr int NM = 16;   // member WGs per group (64 rows each)
constexpr int CH  = 136; // per-lane contiguous k-chunk (1088/8)
constexpr int CHP = 140; // padded chunk stride (12*l8 mod 32 -> all banks)
constexpr int BSTR = 8 * CHP;
constexpr long long OUT1_OFF = (long long)T * B * OF;
constexpr long long OUT2_OFF = (long long)T * B * (OF + OC);
constexpr int RING_U64 = NG * 2 * 2 * 1024;  // [g][slot][b][elem] = 512 KB

// Agent-scope relaxed ops: global_{load,store} sc0 sc1 — bypass L1/L2 (no
// RFO/allocate), coherent at L3, fence-free. Proven (R2/R6/R10/R11/R14).
// sc0-only polling livelocks (R4/R5/R7) — never used.
__device__ __forceinline__ void st_agent_f32(float* p, float v) {
  __hip_atomic_store(p, v, __ATOMIC_RELAXED, __HIP_MEMORY_SCOPE_AGENT);
}
__device__ __forceinline__ void st_agent_u64(unsigned long long* p,
                                             unsigned long long v) {
  __hip_atomic_store(p, v, __ATOMIC_RELAXED, __HIP_MEMORY_SCOPE_AGENT);
}
__device__ __forceinline__ unsigned long long
ld_agent_u64(const unsigned long long* p) {
  return __hip_atomic_load(p, __ATOMIC_RELAXED, __HIP_MEMORY_SCOPE_AGENT);
}

// ---------------------------------------------------------------------------
// Recurrence: 256 persistent WGs x 512 threads (1/CU). R14 schedule with two
// store-drain fixes:
//  (a) rate_all stores are agent-scope (sc0 sc1): plain cached stores of 4B
//      into cold 128MB lines forced an HBM read-for-ownership (~900cyc) that
//      __syncthreads' vmcnt(0) drain then waited on EVERY STEP (R14 FETCH
//      161MB vs R2's 88MB = the RFO signature).
//  (b) the mid-step barrier drains lgkmcnt ONLY (s_barrier without vmcnt
//      drain, R8-proven pattern): phase-0's ring/rate_all stores keep flying
//      under phase 1. The end-of-step barrier remains a full __syncthreads,
//      so each step's stores are drained before the 2-step ring-slot reuse
//      (same-address store ordering stays provable).
// Everything else — geometry, tagged 2-slot ring, ping-pong with early L1
// issue and mid-phase L0 issue, check positions, liveness induction — is
// R14 verbatim.
// ---------------------------------------------------------------------------
__global__ __launch_bounds__(512, 2) void rnn_recur(
    const float* __restrict__ input_sig, const float* __restrict__ rate0,
    const float* __restrict__ i2h_w, const float* __restrict__ i2h_b,
    const float* __restrict__ h2h_w, const float* __restrict__ h2h_b,
    float* __restrict__ rate_all, unsigned long long* __restrict__ ring)
{
  const int tid = threadIdx.x;
  const int bid = blockIdx.x;
  const int g   = bid & (NG - 1);
  const int m   = bid >> 4;
  const int l8  = tid & 7;
  const int jrel = tid >> 3;
  const int j   = m * 64 + jrel;
  const int bG  = g * 2;

  __shared__ float lds[2][BSTR];   // [batch][padded chunks]

  // ---- stationary weights: 68 float2 = 136 fp32/thread
  v2f w2[68];
#pragma unroll
  for (int q = 0; q < 68; ++q) {
    const int k = l8 * CH + q * 2;
    w2[q] = (k < H) ? *(const v2f*)(h2h_w + (long long)j * H + k)
                    : *(const v2f*)(i2h_w + (long long)j * I_ + (k - H));
  }
  const float bsum = h2h_b[j] + i2h_b[j];
  const int posj = (j / CH) * CHP + (j % CH);

  // ---- init: r_{-1} = rate0 and x_0 for both batches (plain cached loads)
  {
    const int b = tid >> 8, u4 = tid & 255;
    const int k0 = u4 * 4, c = k0 / CH, off = k0 - c * CH;
    float4 v = *(const float4*)(rate0 + (long long)(bG + b) * H + k0);
    *(float4*)&lds[b][c * CHP + off] = v;
    if (tid < 32) {
      const int b2 = tid >> 4, iq = tid & 15;
      float4 u = *(const float4*)(input_sig + (long long)(bG + b2) * I_ + iq * 4);
      *(float4*)&lds[b2][7 * CHP + 72 + iq * 4] = u;
    }
  }
  __syncthreads();

  unsigned long long* ringG = ring + (long long)g * (2 * 2 * 1024);
  const int c_  = (2 * tid) / CH;
  const int off_ = 2 * tid - c_ * CH;

  // full compute for batch b at step t (used for phase 0)
  auto phase = [&](int b, int t) {
    const float* Rb = &lds[b][0];
    v2f acc2 = {0.f, 0.f};
#pragma unroll
    for (int q = 0; q < 34; ++q) {
      const v4f rv = *(const v4f*)&Rb[l8 * CHP + q * 4];
      const v2f rlo = __builtin_shufflevector(rv, rv, 0, 1);
      const v2f rhi = __builtin_shufflevector(rv, rv, 2, 3);
      acc2 = __builtin_elementwise_fma(w2[2 * q],     rlo, acc2);
      acc2 = __builtin_elementwise_fma(w2[2 * q + 1], rhi, acc2);
    }
    float acc = acc2.x + acc2.y;
    acc += __shfl_xor(acc, 4, 64);
    acc += __shfl_xor(acc, 2, 64);
    acc += __shfl_xor(acc, 1, 64);
    if (l8 == 0) {
      const float pre  = acc + bsum;
      const float rold = Rb[posj];
      const float rnew = 0.9f * rold + 0.1f * tanhf(pre);
      const unsigned long long pkt =
          ((unsigned long long)(unsigned)(t + 1) << 32) |
          (unsigned long long)__float_as_uint(rnew);
      st_agent_u64(&ringG[((long long)((t & 1) * 2 + b) << 10) + j], pkt);
      st_agent_f32(&rate_all[((long long)t * B + bG + b) * H + j], rnew);
    }
  };

  for (int t = 0; t < T; ++t) {
    // ---- early-issue L1: b1's r_t (slot (t-1)&1, tag t — a full step old)
    unsigned long long v10 = 0, v11 = 0;
    float4 xv1;
    const bool have1 = (t > 0);
    const unsigned long long* p1 =
        &ringG[((long long)((((t - 1) & 1) * 2) + 1) << 10) + 2 * tid];
    if (have1) {
      v10 = ld_agent_u64(p1);
      v11 = ld_agent_u64(p1 + 1);
      if (tid < 16) {
        xv1 = *(const float4*)(input_sig +
            ((long long)t * B + bG + 1) * I_ + tid * 4);
      }
    }

    phase(0, t);   // C0(t): L1 loads fly under this

    if (have1) {
      const unsigned tag = (unsigned)t;
      while ((unsigned)(v10 >> 32) != tag || (unsigned)(v11 >> 32) != tag) {
        v10 = ld_agent_u64(p1);
        v11 = ld_agent_u64(p1 + 1);
      }
      *(float2*)&lds[1][c_ * CHP + off_] = make_float2(
          __uint_as_float((unsigned)v10), __uint_as_float((unsigned)v11));
      if (tid < 16) *(float4*)&lds[1][7 * CHP + 72 + tid * 4] = xv1;
    }
    // mid-step barrier: LDS-drain ONLY (phase-0 stores keep flying; their
    // visibility is enforced by the consumers' tag polls, not by this WG)
    asm volatile("s_waitcnt lgkmcnt(0)\n\ts_barrier" ::: "memory");
    __builtin_amdgcn_sched_barrier(0);

    // ---- C1(t) inline, with MID-PHASE L0 issue ------------------------
    const float* Rb = &lds[1][0];
    v2f acc2 = {0.f, 0.f};
#pragma unroll
    for (int q = 0; q < 17; ++q) {            // first half
      const v4f rv = *(const v4f*)&Rb[l8 * CHP + q * 4];
      const v2f rlo = __builtin_shufflevector(rv, rv, 0, 1);
      const v2f rhi = __builtin_shufflevector(rv, rv, 2, 3);
      acc2 = __builtin_elementwise_fma(w2[2 * q],     rlo, acc2);
      acc2 = __builtin_elementwise_fma(w2[2 * q + 1], rhi, acc2);
    }
    // mid-phase probe: samples L3 ~0.4us after C0's stores (past visibility)
    unsigned long long v00 = 0, v01 = 0;
    float4 xv0;
    const bool have0 = (t + 1 < T);
    const unsigned long long* p0 =
        &ringG[((long long)((t & 1) * 2) << 10) + 2 * tid];
    if (have0) {
      v00 = ld_agent_u64(p0);
      v01 = ld_agent_u64(p0 + 1);
      if (tid < 16) {
        xv0 = *(const float4*)(input_sig +
            ((long long)(t + 1) * B + bG) * I_ + tid * 4);
      }
    }
    __builtin_amdgcn_sched_barrier(0);        // pin the probe issue point
#pragma unroll
    for (int q = 17; q < 34; ++q) {           // second half
      const v4f rv = *(const v4f*)&Rb[l8 * CHP + q * 4];
      const v2f rlo = __builtin_shufflevector(rv, rv, 0, 1);
      const v2f rhi = __builtin_shufflevector(rv, rv, 2, 3);
      acc2 = __builtin_elementwise_fma(w2[2 * q],     rlo, acc2);
      acc2 = __builtin_elementwise_fma(w2[2 * q + 1], rhi, acc2);
    }
    float acc = acc2.x + acc2.y;
    acc += __shfl_xor(acc, 4, 64);
    acc += __shfl_xor(acc, 2, 64);
    acc += __shfl_xor(acc, 1, 64);
    if (l8 == 0) {
      const float pre  = acc + bsum;
      const float rold = Rb[posj];
      const float rnew = 0.9f * rold + 0.1f * tanhf(pre);
      const unsigned long long pkt =
          ((unsigned long long)(unsigned)(t + 1) << 32) |
          (unsigned long long)__float_as_uint(rnew);
      st_agent_u64(&ringG[((long long)((t & 1) * 2 + 1) << 10) + j], pkt);
      st_agent_f32(&rate_all[((long long)t * B + bG + 1) * H + j], rnew);
    }

    if (have0) {
      const unsigned tag = (unsigned)(t + 1);
      while ((unsigned)(v00 >> 32) != tag || (unsigned)(v01 >> 32) != tag) {
        v00 = ld_agent_u64(p0);
        v01 = ld_agent_u64(p0 + 1);
      }
      *(float2*)&lds[0][c_ * CHP + off_] = make_float2(
          __uint_as_float((unsigned)v00), __uint_as_float((unsigned)v01));
      if (tid < 16) *(float4*)&lds[0][7 * CHP + 72 + tid * 4] = xv0;
    }
    // end-of-step barrier: FULL drain (vmcnt+lgkm) — bounds outstanding
    // stores to one step, so the 2-step ring-slot reuse can never reorder
    // same-address stores.
    __syncthreads();
  }
}

// ---------------------------------------------------------------------------
// Readout: C[32768,72] = rate_all[32768,1024] x [h2o_w;h2o_ctx_w]^T + bias
// ---------------------------------------------------------------------------
__global__ __launch_bounds__(256) void rnn_readout(
    const float* __restrict__ rate_all,
    const float* __restrict__ h2o_w, const float* __restrict__ h2o_b,
    const float* __restrict__ h2o_ctx_w, const float* __restrict__ h2o_ctx_b,
    float* __restrict__ out0, float* __restrict__ out1)
{
  constexpr int RB = 128;
  constexpr int HC = 128;
  constexpr int SR = HC + 1;
  __shared__ float rl[RB * SR];
  __shared__ float wl[72 * SR];

  const int tid = threadIdx.x;
  const long long row0 = (long long)blockIdx.x * RB;
  const int rb = tid & 31, og = tid >> 5;

  float acc[4][9];
#pragma unroll
  for (int c = 0; c < 4; ++c)
#pragma unroll
    for (int i = 0; i < 9; ++i) acc[c][i] = 0.f;

  for (int hc = 0; hc < H / HC; ++hc) {
#pragma unroll
    for (int i = 0; i < 16; ++i) {
      const int q = i * 256 + tid;
      const int row = q >> 5, hq = q & 31;
      float4 v = *(const float4*)(rate_all + (row0 + row) * H + hc * HC + hq * 4);
      float* d = &rl[row * SR + hq * 4];
      d[0] = v.x; d[1] = v.y; d[2] = v.z; d[3] = v.w;
    }
#pragma unroll
    for (int i = 0; i < 9; ++i) {
      const int q = i * 256 + tid;
      const int o = q >> 5, hq = q & 31;
      const float* src = (o < OF) ? (h2o_w + (long long)o * H)
                                  : (h2o_ctx_w + (long long)(o - OF) * H);
      float4 v = *(const float4*)(src + hc * HC + hq * 4);
      float* d = &wl[o * SR + hq * 4];
      d[0] = v.x; d[1] = v.y; d[2] = v.z; d[3] = v.w;
    }
    __syncthreads();

#pragma unroll 4
    for (int h = 0; h < HC; ++h) {
      const float r0 = rl[(rb)      * SR + h];
      const float r1 = rl[(rb + 32) * SR + h];
      const float r2 = rl[(rb + 64) * SR + h];
      const float r3 = rl[(rb + 96) * SR + h];
#pragma unroll
      for (int i = 0; i < 9; ++i) {
        const float wv = wl[(og * 9 + i) * SR + h];
        acc[0][i] = fmaf(r0, wv, acc[0][i]);
        acc[1][i] = fmaf(r1, wv, acc[1][i]);
        acc[2][i] = fmaf(r2, wv, acc[2][i]);
        acc[3][i] = fmaf(r3, wv, acc[3][i]);
      }
    }
    __syncthreads();
  }

#pragma unroll
  for (int c = 0; c < 4; ++c) {
    const long long row = row0 + rb + 32 * c;
#pragma unroll
    for (int i = 0; i < 9; ++i) {
      const int o = og * 9 + i;
      if (o < OF) out0[row * OF + o] = acc[c][i] + h2o_b[o];
      else        out1[row * OC + (o - OF)] = acc[c][i] + h2o_ctx_b[o - OF];
    }
  }
}

extern "C" void kernel_launch(void* const* d_in, const int* in_sizes, int n_in,
                              void* d_out, int out_size, void* d_ws, size_t ws_size,
                              hipStream_t stream) {
  (void)in_sizes; (void)n_in; (void)d_ws; (void)ws_size; (void)out_size;
  const float* input_sig = (const float*)d_in[0];
  const float* rate0     = (const float*)d_in[1];
  const float* i2h_w     = (const float*)d_in[2];
  const float* i2h_b     = (const float*)d_in[3];
  const float* h2h_w     = (const float*)d_in[4];
  const float* h2h_b     = (const float*)d_in[5];
  const float* h2o_w     = (const float*)d_in[6];
  const float* h2o_b     = (const float*)d_in[7];
  const float* h2o_ctx_w = (const float*)d_in[8];
  const float* h2o_ctx_b = (const float*)d_in[9];

  float* out      = (float*)d_out;
  float* out0     = out;
  float* out1     = out + OUT1_OFF;
  float* rate_all = out + OUT2_OFF;
  // Tagged 2-slot ring in the first 512 KB of out0 (overwritten by readout).
  unsigned long long* ring = (unsigned long long*)d_out;

  // Zero the ring EVERY call: expected tags are >=1, so zero never matches;
  // stale tags from a previous call/graph-replay would otherwise alias.
  hipMemsetAsync(ring, 0, (size_t)RING_U64 * 8, stream);
  hipLaunchKernelGGL(rnn_recur, dim3(NG * NM), dim3(512), 0, stream,
                     input_sig, rate0, i2h_w, i2h_b, h2h_w, h2h_b,
                     rate_all, ring);
  hipLaunchKernelGGL(rnn_readout, dim3(256), dim3(256), 0, stream,
                     rate_all, h2o_w, h2o_b, h2o_ctx_w, h2o_ctx_b, out0, out1);
}

// Round 16
// 2362.775 us; speedup vs baseline: 2.5974x; 1.0026x over previous
//
#include <hip/hip_runtime.h>

typedef float v2f __attribute__((ext_vector_type(2)));
typedef float v4f __attribute__((ext_vector_type(4)));

constexpr int T  = 1024;
constexpr int B  = 32;
constexpr int I_ = 64;
constexpr int H  = 1024;
constexpr int OF = 64;
constexpr int OC = 8;
constexpr int NG = 16;   // groups (2 batches each)
constexpr int NM = 16;   // member WGs per group (64 rows each)
constexpr int CH  = 136; // per-lane contiguous k-chunk (1088/8)
constexpr int CHP = 140; // padded chunk stride (12*l8 mod 32 -> all banks)
constexpr int BSTR = 8 * CHP;
constexpr long long OUT1_OFF = (long long)T * B * OF;
constexpr long long OUT2_OFF = (long long)T * B * (OF + OC);
constexpr int RING_U64 = NG * 4 * 2 * 1024;  // [g][slot(4)][b][row] = 1 MB

// Agent-scope relaxed ops: global_{load,store} sc0 sc1 — bypass L1/L2,
// coherent at L3, fence-free. Proven (R2/R6/R10/R11/R14/R15). sc0-only
// polling livelocks (R4/R5/R7) — never used.
__device__ __forceinline__ void st_agent_f32(float* p, float v) {
  __hip_atomic_store(p, v, __ATOMIC_RELAXED, __HIP_MEMORY_SCOPE_AGENT);
}
__device__ __forceinline__ void st_agent_u64(unsigned long long* p,
                                             unsigned long long v) {
  __hip_atomic_store(p, v, __ATOMIC_RELAXED, __HIP_MEMORY_SCOPE_AGENT);
}
__device__ __forceinline__ unsigned long long
ld_agent_u64(const unsigned long long* p) {
  return __hip_atomic_load(p, __ATOMIC_RELAXED, __HIP_MEMORY_SCOPE_AGENT);
}

// ---------------------------------------------------------------------------
// Recurrence: 256 persistent WGs x 512 threads (1/CU). R15 schedule with the
// END-OF-STEP vmcnt DRAIN REMOVED:
//   R15's __syncthreads() at step end waited vmcnt(0) — i.e. the ~0.35us L3
//   ack of this step's agent stores, EVERY step. The lap-safety induction
//   never needed it (it rides on data dependence: observing a member's tag
//   t+1 store proves that member's slot-s read completed, since the t+1
//   value was computed FROM the t restage). The only drain-backed property
//   was same-wave same-address store ordering at slot reuse; widening the
//   ring to 4 SLOTS (reuse distance 4 steps ~ 5us; per-wave VMEM issue is
//   in-order and same-address ops take one path to one L3 slice => FIFO)
//   restores that structurally. Both barriers are now lgkm-only.
// Tag-skip impossibility (4 slots): a reader spinning at tag t+4 blocks its
// WG's t+5 stores -> blocks every writer's t+5 checks -> no writer reaches
// t+8 to overwrite. Ring zeroed per call (tags >= 1 never match zero).
// ---------------------------------------------------------------------------
__global__ __launch_bounds__(512, 2) void rnn_recur(
    const float* __restrict__ input_sig, const float* __restrict__ rate0,
    const float* __restrict__ i2h_w, const float* __restrict__ i2h_b,
    const float* __restrict__ h2h_w, const float* __restrict__ h2h_b,
    float* __restrict__ rate_all, unsigned long long* __restrict__ ring)
{
  const int tid = threadIdx.x;
  const int bid = blockIdx.x;
  const int g   = bid & (NG - 1);
  const int m   = bid >> 4;
  const int l8  = tid & 7;
  const int jrel = tid >> 3;
  const int j   = m * 64 + jrel;
  const int bG  = g * 2;

  __shared__ float lds[2][BSTR];   // [batch][padded chunks]

  // ---- stationary weights: 68 float2 = 136 fp32/thread
  v2f w2[68];
#pragma unroll
  for (int q = 0; q < 68; ++q) {
    const int k = l8 * CH + q * 2;
    w2[q] = (k < H) ? *(const v2f*)(h2h_w + (long long)j * H + k)
                    : *(const v2f*)(i2h_w + (long long)j * I_ + (k - H));
  }
  const float bsum = h2h_b[j] + i2h_b[j];
  const int posj = (j / CH) * CHP + (j % CH);

  // ---- init: r_{-1} = rate0 and x_0 for both batches (plain cached loads)
  {
    const int b = tid >> 8, u4 = tid & 255;
    const int k0 = u4 * 4, c = k0 / CH, off = k0 - c * CH;
    float4 v = *(const float4*)(rate0 + (long long)(bG + b) * H + k0);
    *(float4*)&lds[b][c * CHP + off] = v;
    if (tid < 32) {
      const int b2 = tid >> 4, iq = tid & 15;
      float4 u = *(const float4*)(input_sig + (long long)(bG + b2) * I_ + iq * 4);
      *(float4*)&lds[b2][7 * CHP + 72 + iq * 4] = u;
    }
  }
  __syncthreads();

  unsigned long long* ringG = ring + (long long)g * (4 * 2 * 1024);
  const int c_  = (2 * tid) / CH;
  const int off_ = 2 * tid - c_ * CH;

  // full compute for batch b at step t (used for phase 0)
  auto phase = [&](int b, int t) {
    const float* Rb = &lds[b][0];
    v2f acc2 = {0.f, 0.f};
#pragma unroll
    for (int q = 0; q < 34; ++q) {
      const v4f rv = *(const v4f*)&Rb[l8 * CHP + q * 4];
      const v2f rlo = __builtin_shufflevector(rv, rv, 0, 1);
      const v2f rhi = __builtin_shufflevector(rv, rv, 2, 3);
      acc2 = __builtin_elementwise_fma(w2[2 * q],     rlo, acc2);
      acc2 = __builtin_elementwise_fma(w2[2 * q + 1], rhi, acc2);
    }
    float acc = acc2.x + acc2.y;
    acc += __shfl_xor(acc, 4, 64);
    acc += __shfl_xor(acc, 2, 64);
    acc += __shfl_xor(acc, 1, 64);
    if (l8 == 0) {
      const float pre  = acc + bsum;
      const float rold = Rb[posj];
      const float rnew = 0.9f * rold + 0.1f * tanhf(pre);
      const unsigned long long pkt =
          ((unsigned long long)(unsigned)(t + 1) << 32) |
          (unsigned long long)__float_as_uint(rnew);
      st_agent_u64(&ringG[((long long)((t & 3) * 2 + b) << 10) + j], pkt);
      st_agent_f32(&rate_all[((long long)t * B + bG + b) * H + j], rnew);
    }
  };

  for (int t = 0; t < T; ++t) {
    // ---- early-issue L1: b1's r_t (slot (t-1)&3, tag t — a full step old)
    unsigned long long v10 = 0, v11 = 0;
    float4 xv1;
    const bool have1 = (t > 0);
    const unsigned long long* p1 =
        &ringG[((long long)((((t - 1) & 3) * 2) + 1) << 10) + 2 * tid];
    if (have1) {
      v10 = ld_agent_u64(p1);
      v11 = ld_agent_u64(p1 + 1);
      if (tid < 16) {
        xv1 = *(const float4*)(input_sig +
            ((long long)t * B + bG + 1) * I_ + tid * 4);
      }
    }

    phase(0, t);   // C0(t): L1 loads fly under this

    if (have1) {
      const unsigned tag = (unsigned)t;
      while ((unsigned)(v10 >> 32) != tag || (unsigned)(v11 >> 32) != tag) {
        v10 = ld_agent_u64(p1);
        v11 = ld_agent_u64(p1 + 1);
      }
      *(float2*)&lds[1][c_ * CHP + off_] = make_float2(
          __uint_as_float((unsigned)v10), __uint_as_float((unsigned)v11));
      if (tid < 16) *(float4*)&lds[1][7 * CHP + 72 + tid * 4] = xv1;
    }
    // mid-step barrier: LDS-drain only (stores keep flying)
    asm volatile("s_waitcnt lgkmcnt(0)\n\ts_barrier" ::: "memory");
    __builtin_amdgcn_sched_barrier(0);

    // ---- C1(t) inline, with MID-PHASE L0 issue ------------------------
    const float* Rb = &lds[1][0];
    v2f acc2 = {0.f, 0.f};
#pragma unroll
    for (int q = 0; q < 17; ++q) {            // first half
      const v4f rv = *(const v4f*)&Rb[l8 * CHP + q * 4];
      const v2f rlo = __builtin_shufflevector(rv, rv, 0, 1);
      const v2f rhi = __builtin_shufflevector(rv, rv, 2, 3);
      acc2 = __builtin_elementwise_fma(w2[2 * q],     rlo, acc2);
      acc2 = __builtin_elementwise_fma(w2[2 * q + 1], rhi, acc2);
    }
    // mid-phase probe: samples L3 ~0.4us after C0's stores (past visibility)
    unsigned long long v00 = 0, v01 = 0;
    float4 xv0;
    const bool have0 = (t + 1 < T);
    const unsigned long long* p0 =
        &ringG[((long long)((t & 3) * 2) << 10) + 2 * tid];
    if (have0) {
      v00 = ld_agent_u64(p0);
      v01 = ld_agent_u64(p0 + 1);
      if (tid < 16) {
        xv0 = *(const float4*)(input_sig +
            ((long long)(t + 1) * B + bG) * I_ + tid * 4);
      }
    }
    __builtin_amdgcn_sched_barrier(0);        // pin the probe issue point
#pragma unroll
    for (int q = 17; q < 34; ++q) {           // second half
      const v4f rv = *(const v4f*)&Rb[l8 * CHP + q * 4];
      const v2f rlo = __builtin_shufflevector(rv, rv, 0, 1);
      const v2f rhi = __builtin_shufflevector(rv, rv, 2, 3);
      acc2 = __builtin_elementwise_fma(w2[2 * q],     rlo, acc2);
      acc2 = __builtin_elementwise_fma(w2[2 * q + 1], rhi, acc2);
    }
    float acc = acc2.x + acc2.y;
    acc += __shfl_xor(acc, 4, 64);
    acc += __shfl_xor(acc, 2, 64);
    acc += __shfl_xor(acc, 1, 64);
    if (l8 == 0) {
      const float pre  = acc + bsum;
      const float rold = Rb[posj];
      const float rnew = 0.9f * rold + 0.1f * tanhf(pre);
      const unsigned long long pkt =
          ((unsigned long long)(unsigned)(t + 1) << 32) |
          (unsigned long long)__float_as_uint(rnew);
      st_agent_u64(&ringG[((long long)((t & 3) * 2 + 1) << 10) + j], pkt);
      st_agent_f32(&rate_all[((long long)t * B + bG + 1) * H + j], rnew);
    }

    if (have0) {
      const unsigned tag = (unsigned)(t + 1);
      while ((unsigned)(v00 >> 32) != tag || (unsigned)(v01 >> 32) != tag) {
        v00 = ld_agent_u64(p0);
        v01 = ld_agent_u64(p0 + 1);
      }
      *(float2*)&lds[0][c_ * CHP + off_] = make_float2(
          __uint_as_float((unsigned)v00), __uint_as_float((unsigned)v01));
      if (tid < 16) *(float4*)&lds[0][7 * CHP + 72 + tid * 4] = xv0;
    }
    // end-of-step barrier: LDS-drain only — NO vmcnt drain (4-slot ring
    // makes same-address store ordering structural; see header comment)
    asm volatile("s_waitcnt lgkmcnt(0)\n\ts_barrier" ::: "memory");
    __builtin_amdgcn_sched_barrier(0);
  }
}

// ---------------------------------------------------------------------------
// Readout: C[32768,72] = rate_all[32768,1024] x [h2o_w;h2o_ctx_w]^T + bias
// ---------------------------------------------------------------------------
__global__ __launch_bounds__(256) void rnn_readout(
    const float* __restrict__ rate_all,
    const float* __restrict__ h2o_w, const float* __restrict__ h2o_b,
    const float* __restrict__ h2o_ctx_w, const float* __restrict__ h2o_ctx_b,
    float* __restrict__ out0, float* __restrict__ out1)
{
  constexpr int RB = 128;
  constexpr int HC = 128;
  constexpr int SR = HC + 1;
  __shared__ float rl[RB * SR];
  __shared__ float wl[72 * SR];

  const int tid = threadIdx.x;
  const long long row0 = (long long)blockIdx.x * RB;
  const int rb = tid & 31, og = tid >> 5;

  float acc[4][9];
#pragma unroll
  for (int c = 0; c < 4; ++c)
#pragma unroll
    for (int i = 0; i < 9; ++i) acc[c][i] = 0.f;

  for (int hc = 0; hc < H / HC; ++hc) {
#pragma unroll
    for (int i = 0; i < 16; ++i) {
      const int q = i * 256 + tid;
      const int row = q >> 5, hq = q & 31;
      float4 v = *(const float4*)(rate_all + (row0 + row) * H + hc * HC + hq * 4);
      float* d = &rl[row * SR + hq * 4];
      d[0] = v.x; d[1] = v.y; d[2] = v.z; d[3] = v.w;
    }
#pragma unroll
    for (int i = 0; i < 9; ++i) {
      const int q = i * 256 + tid;
      const int o = q >> 5, hq = q & 31;
      const float* src = (o < OF) ? (h2o_w + (long long)o * H)
                                  : (h2o_ctx_w + (long long)(o - OF) * H);
      float4 v = *(const float4*)(src + hc * HC + hq * 4);
      float* d = &wl[o * SR + hq * 4];
      d[0] = v.x; d[1] = v.y; d[2] = v.z; d[3] = v.w;
    }
    __syncthreads();

#pragma unroll 4
    for (int h = 0; h < HC; ++h) {
      const float r0 = rl[(rb)      * SR + h];
      const float r1 = rl[(rb + 32) * SR + h];
      const float r2 = rl[(rb + 64) * SR + h];
      const float r3 = rl[(rb + 96) * SR + h];
#pragma unroll
      for (int i = 0; i < 9; ++i) {
        const float wv = wl[(og * 9 + i) * SR + h];
        acc[0][i] = fmaf(r0, wv, acc[0][i]);
        acc[1][i] = fmaf(r1, wv, acc[1][i]);
        acc[2][i] = fmaf(r2, wv, acc[2][i]);
        acc[3][i] = fmaf(r3, wv, acc[3][i]);
      }
    }
    __syncthreads();
  }

#pragma unroll
  for (int c = 0; c < 4; ++c) {
    const long long row = row0 + rb + 32 * c;
#pragma unroll
    for (int i = 0; i < 9; ++i) {
      const int o = og * 9 + i;
      if (o < OF) out0[row * OF + o] = acc[c][i] + h2o_b[o];
      else        out1[row * OC + (o - OF)] = acc[c][i] + h2o_ctx_b[o - OF];
    }
  }
}

extern "C" void kernel_launch(void* const* d_in, const int* in_sizes, int n_in,
                              void* d_out, int out_size, void* d_ws, size_t ws_size,
                              hipStream_t stream) {
  (void)in_sizes; (void)n_in; (void)d_ws; (void)ws_size; (void)out_size;
  const float* input_sig = (const float*)d_in[0];
  const float* rate0     = (const float*)d_in[1];
  const float* i2h_w     = (const float*)d_in[2];
  const float* i2h_b     = (const float*)d_in[3];
  const float* h2h_w     = (const float*)d_in[4];
  const float* h2h_b     = (const float*)d_in[5];
  const float* h2o_w     = (const float*)d_in[6];
  const float* h2o_b     = (const float*)d_in[7];
  const float* h2o_ctx_w = (const float*)d_in[8];
  const float* h2o_ctx_b = (const float*)d_in[9];

  float* out      = (float*)d_out;
  float* out0     = out;
  float* out1     = out + OUT1_OFF;
  float* rate_all = out + OUT2_OFF;
  // Tagged 4-slot ring in the first 1 MB of out0 (overwritten by readout).
  unsigned long long* ring = (unsigned long long*)d_out;

  // Zero the ring EVERY call: expected tags are >=1, so zero never matches;
  // stale tags from a previous call/graph-replay would otherwise alias.
  hipMemsetAsync(ring, 0, (size_t)RING_U64 * 8, stream);
  hipLaunchKernelGGL(rnn_recur, dim3(NG * NM), dim3(512), 0, stream,
                     input_sig, rate0, i2h_w, i2h_b, h2h_w, h2h_b,
                     rate_all, ring);
  hipLaunchKernelGGL(rnn_readout, dim3(256), dim3(256), 0, stream,
                     rate_all, h2o_w, h2o_b, h2o_ctx_w, h2o_ctx_b, out0, out1);
}